// Round 16
// baseline (194.257 us; speedup 1.0000x reference)
//
#include <hip/hip_runtime.h>

typedef float f4 __attribute__((ext_vector_type(4)));   // clang vector: NT-load legal

// ---------- helpers ----------
__device__ __forceinline__ float readlane_f(float v, int l) {
    return __int_as_float(__builtin_amdgcn_readlane(__float_as_int(v), l));
}

// lgkm-only workgroup barrier: syncs LDS producer->consumer WITHOUT the
// vmcnt(0) drain __syncthreads() emits, so outstanding global (W1 prefetch)
// loads stay in flight across conv.
__device__ __forceinline__ void barrier_lds() {
    asm volatile("s_waitcnt lgkmcnt(0)\n\ts_barrier" ::: "memory");
}

// ---------- single mega-kernel: conv + W1 stream + grid handshake + routing ----
// 256 blocks x 512 thr.  LDS ~66 KB -> 2 blocks/CU capacity, so 256 blocks
// need only 128 CUs: the flag handshake tolerates imperfect dispatch (the
// 107KB/1-per-CU variant required ALL 256 CUs simultaneously -- fragile).
//
// Producer (all blocks): block i owns k rows [i*50, i*50+50): c=i>>3, p0=(i&7)*50.
//   W1 prefetch (10 rows/wave) stays in flight across lgkm-only barriers;
//   conv in TWO 32-image passes (xs[32][309] = 39.6 KB); stream rows 10..49 NT;
//   partials [i][b][j][m] (256B contiguous per (i,b)).
//   Then __syncthreads (vmcnt0 drain: stores committed) -> t0: threadfence
//   (device writeback) + atomicAdd(FLAG, device-scope).
// Consumer (blocks 0..63, b = blockIdx): t0 spins on agent-scope acquire load
//   of FLAG until 256; threadfence; partial-reduce + squash + u2 + routing.
// FLAG zeroed by 4-byte hipMemsetAsync (no dependence on poison semantics).
__global__ __launch_bounds__(512) void mega_kernel(
    const float* __restrict__ X, const float* __restrict__ CW, const float* __restrict__ CB,
    const float* __restrict__ W1, const float* __restrict__ W2,
    float* __restrict__ S1P, unsigned int* __restrict__ FLAG, float* __restrict__ OUT)
{
    int i = blockIdx.x;
    int c = i >> 3, p0 = (i & 7) * 50;
    int t = threadIdx.x;
    int wave = t >> 6, lane = t & 63;

    __shared__ float xs[32][309];   // 11 rows x 28 = 308 (+1 pad), 32 images/pass
    __shared__ float xt[50][64];    // conv output: [p_local][b]
    // routing-phase LDS (disjoint; total ~66 KB)
    __shared__ float part[32][64];
    __shared__ float v1[64];
    __shared__ float u2[10][8][16];
    __shared__ float blog[10][8];
    __shared__ float cw[10][8];
    __shared__ float sv[10][16];
    __shared__ float vv[10][16];
    __shared__ float fac[16];

    int py0 = p0 / 20;

    // ---- W1 prefetch: rows k0..k0+9 for j = wave (read-only: safe to keep
    //      outstanding across lgkm-only barriers) ----
    int k0 = c * 400 + p0;
    const f4* Wp = reinterpret_cast<const f4*>(W1) + (size_t)wave * 819200
                   + (size_t)k0 * 64 + lane;
    f4 pre[10];
    #pragma unroll
    for (int q = 0; q < 10; ++q)
        pre[q] = __builtin_nontemporal_load(Wp + (size_t)q * 64);

    float bias = CB[c];
    const float* wcg = CW + c * 81;
    float w[81];                    // block-uniform -> compiler scalarizes to SGPRs
    #pragma unroll
    for (int q = 0; q < 81; ++q) w[q] = wcg[q];

    // ---- Phase A: conv in two 32-image passes ----
    for (int h = 0; h < 2; ++h) {
        {   // stage 32 images x 308 floats (77 f4 each), 16 thr/image
            int b2 = t >> 4, q = t & 15;
            const f4* src = reinterpret_cast<const f4*>(X + (size_t)(b2 + 32 * h) * 784 + py0 * 28);
            #pragma unroll
            for (int s = 0; s < 5; ++s) {
                int idx4 = q + 16 * s;
                if (idx4 < 77) {
                    f4 v = src[idx4];
                    float* d = &xs[b2][idx4 * 4];
                    d[0] = v.x; d[1] = v.y; d[2] = v.z; d[3] = v.w;
                }
            }
        }
        barrier_lds();
        {   // thread (psub = t>>5 in 0..15, b2 = t&31)
            int psub = t >> 5, b2 = t & 31;
            for (int pl = psub; pl < 50; pl += 16) {
                int p = p0 + pl;
                int py = p / 20, px = p - py * 20;
                const float* xrow = &xs[b2][(py - py0) * 28 + px];
                float acc = bias;
                #pragma unroll
                for (int dy = 0; dy < 9; ++dy)
                    #pragma unroll
                    for (int dx = 0; dx < 9; ++dx)
                        acc = fmaf(xrow[dy * 28 + dx], w[dy * 9 + dx], acc);
                xt[pl][b2 + 32 * h] = acc > 0.f ? acc : 0.f;   // relu
            }
        }
        barrier_lds();   // h=0: protect xs overwrite; h=1: xt complete
    }

    // ---- Phase B: consume prefetch, then stream rows 10..49 ----
    float acc[8] = {0.f,0.f,0.f,0.f,0.f,0.f,0.f,0.f};
    #pragma unroll
    for (int kk = 0; kk < 10; ++kk) {
        f4 wv = pre[kk];
        float xv = xt[kk][lane];
        float s = (wv.x + wv.y) + (wv.z + wv.w);
        s += __shfl_xor(s, 1);
        s += __shfl_xor(s, 2);
        s += __shfl_xor(s, 4);                              // Wsum[m] in lane group m
        #pragma unroll
        for (int m = 0; m < 8; ++m)
            acc[m] = fmaf(xv, readlane_f(s, m * 8), acc[m]);
    }
    Wp += (size_t)10 * 64;
    #pragma unroll 10
    for (int kk = 10; kk < 50; ++kk) {
        f4 wv = __builtin_nontemporal_load(Wp); Wp += 64;   // stream-once: bypass L2
        float xv = xt[kk][lane];
        float s = (wv.x + wv.y) + (wv.z + wv.w);
        s += __shfl_xor(s, 1);
        s += __shfl_xor(s, 2);
        s += __shfl_xor(s, 4);
        #pragma unroll
        for (int m = 0; m < 8; ++m)
            acc[m] = fmaf(xv, readlane_f(s, m * 8), acc[m]);
    }

    // final partial for (b=lane, j=wave, m): layout [i][b][j][m]
    {
        float* dst = S1P + (((size_t)i * 64 + lane) * 8 + wave) * 8;
        f4 lo = {acc[0], acc[1], acc[2], acc[3]};
        f4 hi = {acc[4], acc[5], acc[6], acc[7]};
        reinterpret_cast<f4*>(dst)[0] = lo;
        reinterpret_cast<f4*>(dst)[1] = hi;
    }

    // ---- handshake: publish partials, signal ----
    __syncthreads();                 // vmcnt(0) drain: block's stores committed
    if (t == 0) {
        __threadfence();             // device-scope writeback (cross-XCD visibility)
        atomicAdd(FLAG, 1u);         // device-scope by default
    }
    if (i >= 64) return;             // block-uniform exit

    // ---- consumer: wait for all 256 producers ----
    int b = i;
    if (t == 0) {
        while (__hip_atomic_load(FLAG, __ATOMIC_ACQUIRE, __HIP_MEMORY_SCOPE_AGENT) < 256u)
            __builtin_amdgcn_s_sleep(1);
    }
    __syncthreads();
    __threadfence();                 // acquire: invalidate stale lines before reads

    // ---- partial reduce: s1[b][j][m] = sum_i S1P[i][b][j][m] ----
    {   // thread (q = t&15: f4 within 64-float row, r = t>>4 in 0..31: i mod 32)
        int q = t & 15, r = t >> 4;
        const f4* base = reinterpret_cast<const f4*>(S1P) + ((size_t)r * 64 + b) * 16 + q;
        f4 a = {0.f, 0.f, 0.f, 0.f};
        #pragma unroll
        for (int s = 0; s < 8; ++s)
            a += base[(size_t)s * 32768];   // i += 32 -> 32*1024 f4
        part[r][q * 4 + 0] = a.x;
        part[r][q * 4 + 1] = a.y;
        part[r][q * 4 + 2] = a.z;
        part[r][q * 4 + 3] = a.w;
    }
    __syncthreads();
    if (t < 64) {
        float v = 0.f;
        #pragma unroll
        for (int r = 0; r < 32; ++r) v += part[r][t];
        v1[t] = v * 0.125f;             // softmax(0) over 8 caps = 1/8
    }
    if (t >= 64 && t < 144) { int q = t - 64; blog[q >> 3][q & 7] = 0.f; }
    __syncthreads();
    if (t < 8) {   // squash per primary capsule: |s|/(1+|s|^2) * s
        float n2 = 0.f;
        #pragma unroll
        for (int m = 0; m < 8; ++m) { float x = v1[t * 8 + m]; n2 = fmaf(x, x, n2); }
        float n = sqrtf(n2);
        fac[t] = n / (1.f + n2);
    }
    __syncthreads();
    if (t < 64) v1[t] *= fac[t >> 3];
    __syncthreads();

    // u2[j][k][m] = sum_c W2[j,k,m,c] * v1[k][c]
    for (int idx = t; idx < 1280; idx += 512) {
        int j = idx >> 7;
        int r = idx & 127;
        int k = r >> 4, m = r & 15;
        const float* wp = W2 + idx * 8;   // [j][k][m][c] contiguous
        float a = 0.f;
        #pragma unroll
        for (int cc = 0; cc < 8; ++cc) a = fmaf(wp[cc], v1[k * 8 + cc], a);
        u2[j][k][m] = a;
    }
    __syncthreads();

    for (int it = 0; it < 3; ++it) {
        if (t < 8) {   // softmax over 10 classes for k = t
            float mx = -1e30f;
            #pragma unroll
            for (int j = 0; j < 10; ++j) mx = fmaxf(mx, blog[j][t]);
            float e[10], se = 0.f;
            #pragma unroll
            for (int j = 0; j < 10; ++j) { e[j] = expf(blog[j][t] - mx); se += e[j]; }
            float inv = 1.f / se;
            #pragma unroll
            for (int j = 0; j < 10; ++j) cw[j][t] = e[j] * inv;
        }
        __syncthreads();
        if (t < 160) {   // s[j][m] = sum_k c[j][k] * u2[j][k][m]
            int j = t >> 4, m = t & 15;
            float a = 0.f;
            #pragma unroll
            for (int k = 0; k < 8; ++k) a = fmaf(cw[j][k], u2[j][k][m], a);
            sv[j][m] = a;
        }
        __syncthreads();
        if (t < 10) {    // squash factor per class
            float n2 = 0.f;
            #pragma unroll
            for (int m = 0; m < 16; ++m) { float x = sv[t][m]; n2 = fmaf(x, x, n2); }
            float n = sqrtf(n2);
            fac[t] = n / (1.f + n2);
        }
        __syncthreads();
        if (t < 160) { int j = t >> 4, m = t & 15; vv[j][m] = sv[j][m] * fac[j]; }
        __syncthreads();
        if (it < 2) {
            if (t < 80) {   // b[j][k] += sum_m u2[j][k][m] * v[j][m]
                int j = t >> 3, k = t & 7;
                float d = 0.f;
                #pragma unroll
                for (int m = 0; m < 16; ++m) d = fmaf(u2[j][k][m], vv[j][m], d);
                blog[j][k] += d;
            }
            __syncthreads();
        }
    }
    if (t < 160) OUT[b * 160 + t] = vv[t >> 4][t & 15];
}

// ---------- launch ----------
extern "C" void kernel_launch(void* const* d_in, const int* in_sizes, int n_in,
                              void* d_out, int out_size, void* d_ws, size_t ws_size,
                              hipStream_t stream) {
    const float* X  = (const float*)d_in[0];
    const float* CW = (const float*)d_in[1];
    const float* CB = (const float*)d_in[2];
    const float* W1 = (const float*)d_in[3];
    const float* W2 = (const float*)d_in[4];
    float* S1P = (float*)d_ws;                               // 256*4096 f32 = 4 MB
    unsigned int* FLAG = (unsigned int*)((char*)d_ws + 4194304);
    float* OUT = (float*)d_out;

    hipMemsetAsync(FLAG, 0, 4, stream);                      // capturable memset node
    mega_kernel<<<256, 512, 0, stream>>>(X, CW, CB, W1, W2, S1P, FLAG, OUT);
}

// Round 17
// 188.544 us; speedup vs baseline: 1.0303x; 1.0303x over previous
//
#include <hip/hip_runtime.h>

typedef float f4 __attribute__((ext_vector_type(4)));   // clang vector: NT-load legal

// ---------- helpers ----------
__device__ __forceinline__ float readlane_f(float v, int l) {
    return __int_as_float(__builtin_amdgcn_readlane(__float_as_int(v), l));
}

// lgkm-only workgroup barrier: syncs LDS producer->consumer WITHOUT the
// vmcnt(0) drain __syncthreads() emits, so outstanding global (W1 prefetch)
// loads stay in flight across conv.
__device__ __forceinline__ void barrier_lds() {
    asm volatile("s_waitcnt lgkmcnt(0)\n\ts_barrier" ::: "memory");
}

// ---------- single mega-kernel: conv + W1 stream + grid handshake + routing ----
// 256 blocks x 512 thr, LDS ~66 KB (2 blocks/CU capacity -> dispatch-robust).
// ROUND-16 MEASURED: producer phase ~26us (healthy), consumer tail ~41us for
// ~5us of work -- a fence/invalidate storm: 512 per-wave device threadfences
// (each = full XCD-L2 writeback-inv) + ACQUIRE poll every ~64 cycles.
// FIX: poll sparsely (s_sleep(32) ~0.9us) and drop the per-thread threadfence;
// the final ACQUIRE poll's invalidate (per-CU L1 + per-XCD L2) is the data
// barrier for the whole block, __syncthreads orders other waves after it.
//
// Producer (all blocks): block i owns k rows [i*50,i*50+50): c=i>>3, p0=(i&7)*50.
//   W1 prefetch (10 rows/wave) in flight across lgkm-only barriers; conv in two
//   32-image passes; stream rows 10..49 NT; partials [i][b][j][m] (256B/row).
//   __syncthreads (vmcnt0: stores committed) -> t0: threadfence (L2 writeback,
//   cross-XCD visibility) + atomicAdd(FLAG, device-scope).
// Consumer (blocks 0..63, b=blockIdx): t0 sparse-polls FLAG to 256 (acquire);
//   __syncthreads; partial-reduce + squash + u2 + 3-iter routing.
// FLAG zeroed by 4-byte hipMemsetAsync (graph node, re-runs every replay).
__global__ __launch_bounds__(512) void mega_kernel(
    const float* __restrict__ X, const float* __restrict__ CW, const float* __restrict__ CB,
    const float* __restrict__ W1, const float* __restrict__ W2,
    float* __restrict__ S1P, unsigned int* __restrict__ FLAG, float* __restrict__ OUT)
{
    int i = blockIdx.x;
    int c = i >> 3, p0 = (i & 7) * 50;
    int t = threadIdx.x;
    int wave = t >> 6, lane = t & 63;

    __shared__ float xs[32][309];   // 11 rows x 28 = 308 (+1 pad), 32 images/pass
    __shared__ float xt[50][64];    // conv output: [p_local][b]
    // routing-phase LDS (disjoint; total ~66 KB)
    __shared__ float part[32][64];
    __shared__ float v1[64];
    __shared__ float u2[10][8][16];
    __shared__ float blog[10][8];
    __shared__ float cw[10][8];
    __shared__ float sv[10][16];
    __shared__ float vv[10][16];
    __shared__ float fac[16];

    int py0 = p0 / 20;

    // ---- W1 prefetch: rows k0..k0+9 for j = wave ----
    int k0 = c * 400 + p0;
    const f4* Wp = reinterpret_cast<const f4*>(W1) + (size_t)wave * 819200
                   + (size_t)k0 * 64 + lane;
    f4 pre[10];
    #pragma unroll
    for (int q = 0; q < 10; ++q)
        pre[q] = __builtin_nontemporal_load(Wp + (size_t)q * 64);

    float bias = CB[c];
    const float* wcg = CW + c * 81;
    float w[81];                    // block-uniform -> compiler scalarizes to SGPRs
    #pragma unroll
    for (int q = 0; q < 81; ++q) w[q] = wcg[q];

    // ---- Phase A: conv in two 32-image passes ----
    for (int h = 0; h < 2; ++h) {
        {   // stage 32 images x 308 floats (77 f4 each), 16 thr/image
            int b2 = t >> 4, q = t & 15;
            const f4* src = reinterpret_cast<const f4*>(X + (size_t)(b2 + 32 * h) * 784 + py0 * 28);
            #pragma unroll
            for (int s = 0; s < 5; ++s) {
                int idx4 = q + 16 * s;
                if (idx4 < 77) {
                    f4 v = src[idx4];
                    float* d = &xs[b2][idx4 * 4];
                    d[0] = v.x; d[1] = v.y; d[2] = v.z; d[3] = v.w;
                }
            }
        }
        barrier_lds();
        {   // thread (psub = t>>5 in 0..15, b2 = t&31)
            int psub = t >> 5, b2 = t & 31;
            for (int pl = psub; pl < 50; pl += 16) {
                int p = p0 + pl;
                int py = p / 20, px = p - py * 20;
                const float* xrow = &xs[b2][(py - py0) * 28 + px];
                float acc = bias;
                #pragma unroll
                for (int dy = 0; dy < 9; ++dy)
                    #pragma unroll
                    for (int dx = 0; dx < 9; ++dx)
                        acc = fmaf(xrow[dy * 28 + dx], w[dy * 9 + dx], acc);
                xt[pl][b2 + 32 * h] = acc > 0.f ? acc : 0.f;   // relu
            }
        }
        barrier_lds();   // h=0: protect xs overwrite; h=1: xt complete
    }

    // ---- Phase B: consume prefetch, then stream rows 10..49 ----
    float acc[8] = {0.f,0.f,0.f,0.f,0.f,0.f,0.f,0.f};
    #pragma unroll
    for (int kk = 0; kk < 10; ++kk) {
        f4 wv = pre[kk];
        float xv = xt[kk][lane];
        float s = (wv.x + wv.y) + (wv.z + wv.w);
        s += __shfl_xor(s, 1);
        s += __shfl_xor(s, 2);
        s += __shfl_xor(s, 4);                              // Wsum[m] in lane group m
        #pragma unroll
        for (int m = 0; m < 8; ++m)
            acc[m] = fmaf(xv, readlane_f(s, m * 8), acc[m]);
    }
    Wp += (size_t)10 * 64;
    #pragma unroll 10
    for (int kk = 10; kk < 50; ++kk) {
        f4 wv = __builtin_nontemporal_load(Wp); Wp += 64;   // stream-once: bypass L2
        float xv = xt[kk][lane];
        float s = (wv.x + wv.y) + (wv.z + wv.w);
        s += __shfl_xor(s, 1);
        s += __shfl_xor(s, 2);
        s += __shfl_xor(s, 4);
        #pragma unroll
        for (int m = 0; m < 8; ++m)
            acc[m] = fmaf(xv, readlane_f(s, m * 8), acc[m]);
    }

    // final partial for (b=lane, j=wave, m): layout [i][b][j][m]
    {
        float* dst = S1P + (((size_t)i * 64 + lane) * 8 + wave) * 8;
        f4 lo = {acc[0], acc[1], acc[2], acc[3]};
        f4 hi = {acc[4], acc[5], acc[6], acc[7]};
        reinterpret_cast<f4*>(dst)[0] = lo;
        reinterpret_cast<f4*>(dst)[1] = hi;
    }

    // ---- handshake: publish partials, signal ----
    __syncthreads();                 // vmcnt(0) drain: block's stores committed
    if (t == 0) {
        __threadfence();             // ONE per block: L2 writeback (cross-XCD vis)
        atomicAdd(FLAG, 1u);         // device-scope by default
    }
    if (i >= 64) return;             // block-uniform exit

    // ---- consumer: wait for all 256 producers (sparse acquire poll) ----
    int b = i;
    if (t == 0) {
        // s_sleep(32) ~ 0.9us/poll: ~30x fewer L2 invalidates than s_sleep(1).
        // The terminating ACQUIRE load's invalidate (this CU's L1 + XCD L2) is
        // the block-wide data barrier; no per-thread threadfence (round-16's
        // 512 per-wave wbl2 storm = the 41us consumer tail).
        while (__hip_atomic_load(FLAG, __ATOMIC_ACQUIRE, __HIP_MEMORY_SCOPE_AGENT) < 256u)
            __builtin_amdgcn_s_sleep(32);
    }
    __syncthreads();                 // orders all waves' reads after t0's acquire

    // ---- partial reduce: s1[b][j][m] = sum_i S1P[i][b][j][m] ----
    {   // thread (q = t&15: f4 within 64-float row, r = t>>4 in 0..31: i mod 32)
        int q = t & 15, r = t >> 4;
        const f4* base = reinterpret_cast<const f4*>(S1P) + ((size_t)r * 64 + b) * 16 + q;
        f4 a = {0.f, 0.f, 0.f, 0.f};
        #pragma unroll
        for (int s = 0; s < 8; ++s)
            a += base[(size_t)s * 32768];   // i += 32 -> 32*1024 f4
        part[r][q * 4 + 0] = a.x;
        part[r][q * 4 + 1] = a.y;
        part[r][q * 4 + 2] = a.z;
        part[r][q * 4 + 3] = a.w;
    }
    __syncthreads();
    if (t < 64) {
        float v = 0.f;
        #pragma unroll
        for (int r = 0; r < 32; ++r) v += part[r][t];
        v1[t] = v * 0.125f;             // softmax(0) over 8 caps = 1/8
    }
    if (t >= 64 && t < 144) { int q = t - 64; blog[q >> 3][q & 7] = 0.f; }
    __syncthreads();
    if (t < 8) {   // squash per primary capsule: |s|/(1+|s|^2) * s
        float n2 = 0.f;
        #pragma unroll
        for (int m = 0; m < 8; ++m) { float x = v1[t * 8 + m]; n2 = fmaf(x, x, n2); }
        float n = sqrtf(n2);
        fac[t] = n / (1.f + n2);
    }
    __syncthreads();
    if (t < 64) v1[t] *= fac[t >> 3];
    __syncthreads();

    // u2[j][k][m] = sum_c W2[j,k,m,c] * v1[k][c]
    for (int idx = t; idx < 1280; idx += 512) {
        int j = idx >> 7;
        int r = idx & 127;
        int k = r >> 4, m = r & 15;
        const float* wp = W2 + idx * 8;   // [j][k][m][c] contiguous
        float a = 0.f;
        #pragma unroll
        for (int cc = 0; cc < 8; ++cc) a = fmaf(wp[cc], v1[k * 8 + cc], a);
        u2[j][k][m] = a;
    }
    __syncthreads();

    for (int it = 0; it < 3; ++it) {
        if (t < 8) {   // softmax over 10 classes for k = t
            float mx = -1e30f;
            #pragma unroll
            for (int j = 0; j < 10; ++j) mx = fmaxf(mx, blog[j][t]);
            float e[10], se = 0.f;
            #pragma unroll
            for (int j = 0; j < 10; ++j) { e[j] = expf(blog[j][t] - mx); se += e[j]; }
            float inv = 1.f / se;
            #pragma unroll
            for (int j = 0; j < 10; ++j) cw[j][t] = e[j] * inv;
        }
        __syncthreads();
        if (t < 160) {   // s[j][m] = sum_k c[j][k] * u2[j][k][m]
            int j = t >> 4, m = t & 15;
            float a = 0.f;
            #pragma unroll
            for (int k = 0; k < 8; ++k) a = fmaf(cw[j][k], u2[j][k][m], a);
            sv[j][m] = a;
        }
        __syncthreads();
        if (t < 10) {    // squash factor per class
            float n2 = 0.f;
            #pragma unroll
            for (int m = 0; m < 16; ++m) { float x = sv[t][m]; n2 = fmaf(x, x, n2); }
            float n = sqrtf(n2);
            fac[t] = n / (1.f + n2);
        }
        __syncthreads();
        if (t < 160) { int j = t >> 4, m = t & 15; vv[j][m] = sv[j][m] * fac[j]; }
        __syncthreads();
        if (it < 2) {
            if (t < 80) {   // b[j][k] += sum_m u2[j][k][m] * v[j][m]
                int j = t >> 3, k = t & 7;
                float d = 0.f;
                #pragma unroll
                for (int m = 0; m < 16; ++m) d = fmaf(u2[j][k][m], vv[j][m], d);
                blog[j][k] += d;
            }
            __syncthreads();
        }
    }
    if (t < 160) OUT[b * 160 + t] = vv[t >> 4][t & 15];
}

// ---------- launch ----------
extern "C" void kernel_launch(void* const* d_in, const int* in_sizes, int n_in,
                              void* d_out, int out_size, void* d_ws, size_t ws_size,
                              hipStream_t stream) {
    const float* X  = (const float*)d_in[0];
    const float* CW = (const float*)d_in[1];
    const float* CB = (const float*)d_in[2];
    const float* W1 = (const float*)d_in[3];
    const float* W2 = (const float*)d_in[4];
    float* S1P = (float*)d_ws;                               // 256*4096 f32 = 4 MB
    unsigned int* FLAG = (unsigned int*)((char*)d_ws + 4194304);
    float* OUT = (float*)d_out;

    hipMemsetAsync(FLAG, 0, 4, stream);                      // capturable memset node
    mega_kernel<<<256, 512, 0, stream>>>(X, CW, CB, W1, W2, S1P, FLAG, OUT);
}